// Round 1
// baseline (524.125 us; speedup 1.0000x reference)
//
#include <hip/hip_runtime.h>
#include <hip/hip_bf16.h>

// Problem constants
#define BATCH 32
#define CIN   256
#define COUT  256
#define HH    56
#define HP    58      // padded
#define NEXP  5
#define HID   65

// Workspace layout (bytes)
#define OFF_S     0                         // 32*256*4      = 32768
#define OFF_ATTN  32768                     // 32*5*4        = 640
#define OFF_WAL   65536                     // 5*9*256*256*4 = 11796480
#define OFF_AGGW  (12u*1024u*1024u)         // 32*9*256*256*2 = 37748736
#define OFF_XPAD  (48u*1024u*1024u)         // 32*58*58*256*2 = 55115776
// total ~ 101 MB

typedef __bf16 bf16x8 __attribute__((ext_vector_type(8)));
typedef float  f32x4  __attribute__((ext_vector_type(4)));

__device__ __forceinline__ unsigned short f2bf(float f) {
    unsigned int u = __float_as_uint(f);
    unsigned int r = (u + 0x7FFFu + ((u >> 16) & 1u)) >> 16;
    return (unsigned short)r;
}

// ---------------------------------------------------------------------------
// k1: zero the 1-px border of xpad (NHWC padded bf16)
// grid (4, 32), block 256
__global__ void border_kernel(unsigned short* __restrict__ xpad) {
    const int b = blockIdx.y, seg = blockIdx.x, tid = threadIdx.x;
    const uint4 z = make_uint4(0, 0, 0, 0);
    if (seg < 2) {
        const int y = seg ? (HP - 1) : 0;
        uint4* p = (uint4*)(xpad + (size_t)((b * HP + y) * HP) * 256);
        for (int i = tid; i < HP * 256 / 8; i += 256) p[i] = z;
    } else {
        const int xx = (seg == 2) ? 0 : (HP - 1);
        for (int i = tid; i < HP * 32; i += 256) {   // 58 rows x 32 uint4
            const int y = i >> 5, sub = i & 31;
            uint4* p = (uint4*)(xpad + (size_t)(((b * HP + y) * HP + xx)) * 256);
            p[sub] = z;
        }
    }
}

// ---------------------------------------------------------------------------
// k2: x (NCHW f32) -> xpad interior (NHWC bf16), fused global-avg-pool partials
// grid (56, 32), block 256
__global__ void xprep_kernel(const float* __restrict__ x,
                             unsigned short* __restrict__ xpad,
                             float* __restrict__ s) {
    const int y = blockIdx.x, b = blockIdx.y;
    const int tid = threadIdx.x, lane = tid & 63, wg = tid >> 6;
    __shared__ unsigned short lds[HH * 258];   // [x][c], c padded 256->258

    for (int c = wg; c < 256; c += 4) {
        float v = 0.f;
        if (lane < HH) v = x[(size_t)((b * 256 + c) * HH + y) * HH + lane];
        if (lane < HH) lds[lane * 258 + c] = f2bf(v);
        float sum = v;
        #pragma unroll
        for (int off = 32; off > 0; off >>= 1) sum += __shfl_down(sum, off, 64);
        if (lane == 0) atomicAdd(&s[b * 256 + c], sum);
    }
    __syncthreads();
    for (int xx = 0; xx < HH; ++xx) {
        xpad[(size_t)(((b * HP + (y + 1)) * HP + (xx + 1))) * 256 + tid] =
            lds[xx * 258 + tid];
    }
}

// ---------------------------------------------------------------------------
// k3: attention MLP.  grid 32, block 128
__global__ void attn_kernel(const float* __restrict__ s,
                            const float* __restrict__ w1,
                            const float* __restrict__ w2,
                            const float* __restrict__ b2,
                            float* __restrict__ attn) {
    const int b = blockIdx.x, tid = threadIdx.x;
    __shared__ float sm[256];
    __shared__ float hm[HID];
    for (int i = tid; i < 256; i += 128) sm[i] = s[b * 256 + i] * (1.f / 3136.f);
    __syncthreads();
    if (tid < HID) {
        float acc = 0.f;
        for (int c = 0; c < 256; ++c) acc += sm[c] * w1[tid * 256 + c];
        hm[tid] = fmaxf(acc, 0.f);
    }
    __syncthreads();
    if (tid < NEXP) {
        float acc = b2[tid];
        for (int j = 0; j < HID; ++j) acc += hm[j] * w2[tid * HID + j];
        attn[b * NEXP + tid] = 1.f / (1.f + expf(-acc));
    }
}

// ---------------------------------------------------------------------------
// k4: w_aligned[e,t,j,i] = sum_o align[e,j,o] * W[e,o,i*9+t]   (fp32)
// grid (18, 4, 5): n-tile(128), j-tile(64), e.  block 256.
__global__ void align_kernel(const float* __restrict__ am,
                             const float* __restrict__ w,
                             float* __restrict__ wal) {
    const int nt = blockIdx.x, jt = blockIdx.y, e = blockIdx.z;
    const int tid = threadIdx.x;
    const int tj = tid >> 5, tn = tid & 31;
    __shared__ float At[64][33];
    __shared__ float Wt[32][128];
    float acc[8][4];
    #pragma unroll
    for (int a = 0; a < 8; ++a)
        #pragma unroll
        for (int c = 0; c < 4; ++c) acc[a][c] = 0.f;

    for (int o0 = 0; o0 < 256; o0 += 32) {
        {   // stage align tile 64x32
            const int row = tid >> 2, col = (tid & 3) * 8;
            const float* src = am + (size_t)((e * 256) + jt * 64 + row) * 256 + o0 + col;
            float4 v0 = *(const float4*)(src);
            float4 v1 = *(const float4*)(src + 4);
            *(float4*)&At[row][col] = v0;
            *(float4*)&At[row][col + 4] = v1;
        }
        {   // stage W tile 32x128
            const int row = tid >> 3, col = (tid & 7) * 16;
            const float* src = w + (size_t)((e * 256) + o0 + row) * 2304 + nt * 128 + col;
            #pragma unroll
            for (int q = 0; q < 4; ++q)
                *(float4*)&Wt[row][col + q * 4] = *(const float4*)(src + q * 4);
        }
        __syncthreads();
        for (int k = 0; k < 32; ++k) {
            float wv[4];
            #pragma unroll
            for (int c = 0; c < 4; ++c) wv[c] = Wt[k][tn * 4 + c];
            #pragma unroll
            for (int a = 0; a < 8; ++a) {
                const float av = At[tj * 8 + a][k];
                #pragma unroll
                for (int c = 0; c < 4; ++c) acc[a][c] += av * wv[c];
            }
        }
        __syncthreads();
    }
    #pragma unroll
    for (int a = 0; a < 8; ++a) {
        const int j = jt * 64 + tj * 8 + a;
        #pragma unroll
        for (int c = 0; c < 4; ++c) {
            const int n = nt * 128 + tn * 4 + c;
            const int t = n % 9, i = n / 9;
            wal[(size_t)(((e * 9 + t) * 256 + j)) * 256 + i] = acc[a][c];
        }
    }
}

// ---------------------------------------------------------------------------
// k5: agg_w[b,t,j,i] (bf16) = sum_e attn[b,e] * wal[e,t,j,i]
// grid 2304 (t*256+j), block 256 (i)
__global__ void agg_kernel(const float* __restrict__ wal,
                           const float* __restrict__ attn,
                           unsigned short* __restrict__ aggw) {
    const int t = blockIdx.x >> 8, j = blockIdx.x & 255, i = threadIdx.x;
    __shared__ float at[BATCH * NEXP];
    if (threadIdx.x < BATCH * NEXP) at[threadIdx.x] = attn[threadIdx.x];
    float wv[NEXP];
    #pragma unroll
    for (int e = 0; e < NEXP; ++e)
        wv[e] = wal[(size_t)(((e * 9 + t) * 256 + j)) * 256 + i];
    __syncthreads();
    for (int b = 0; b < BATCH; ++b) {
        float acc = 0.f;
        #pragma unroll
        for (int e = 0; e < NEXP; ++e) acc += at[b * NEXP + e] * wv[e];
        aggw[(size_t)(((b * 9 + t) * 256 + j)) * 256 + i] = f2bf(acc);
    }
}

// ---------------------------------------------------------------------------
// k6: implicit-GEMM conv. block = 1 sample x 256 couts x 2 output rows (112 px)
// grid (28, 32), block 256 (4 waves; wave w -> couts [64w, 64w+64))
// LDS: input slab [4 rows][58 cols][32 ch pad->40] bf16
#define CPAD 40
#define COLB (CPAD * 2)          // 80 B per col
#define ROWB (HP * COLB)         // 4640 B per row
__global__ __launch_bounds__(256, 2) void conv_kernel(
        const unsigned short* __restrict__ xpad,
        const unsigned short* __restrict__ aggw,
        float* __restrict__ out) {
    const int b = blockIdx.y;
    const int y0 = blockIdx.x * 2;
    const int tid = threadIdx.x;
    const int wave = tid >> 6, lane = tid & 63;
    const int g = lane >> 4, ln = lane & 15;

    __shared__ unsigned short lds[4 * HP * CPAD];

    f32x4 acc[4][7];
    #pragma unroll
    for (int mt = 0; mt < 4; ++mt)
        #pragma unroll
        for (int nt = 0; nt < 7; ++nt) acc[mt][nt] = (f32x4){0.f, 0.f, 0.f, 0.f};

    // per-lane B-fragment base byte offsets (ky=kx=0)
    int nbase[7];
    #pragma unroll
    for (int nt = 0; nt < 7; ++nt) {
        const int p = nt * 16 + ln;
        const int yy = p / HH, xx = p % HH;
        nbase[nt] = (yy * HP + xx) * COLB + g * 16;
    }
    const int mwave = wave * 64;

    #pragma unroll 1
    for (int c0 = 0; c0 < 256; c0 += 32) {
        // stage 4 rows x 58 cols x 32 ch = 928 x 16B
        #pragma unroll
        for (int it = 0; it < 4; ++it) {
            const int idx = it * 256 + tid;
            if (idx < 928) {
                const int row = idx / 232;
                const int rem = idx - row * 232;
                const int col = rem >> 2, sub = rem & 3;
                const uint4 v = *(const uint4*)(xpad +
                    (size_t)(((b * HP + y0 + row) * HP + col)) * 256 + c0 + sub * 8);
                *(uint4*)((char*)lds + row * ROWB + col * COLB + sub * 16) = v;
            }
        }
        __syncthreads();

        #pragma unroll
        for (int ky = 0; ky < 3; ++ky) {
            #pragma unroll
            for (int kx = 0; kx < 3; ++kx) {
                const int tap = ky * 3 + kx;
                bf16x8 a[4];
                const unsigned short* ap = aggw +
                    (size_t)(((b * 9 + tap) * 256 + mwave + ln)) * 256 + c0 + g * 8;
                #pragma unroll
                for (int mt = 0; mt < 4; ++mt)
                    a[mt] = *(const bf16x8*)(ap + mt * 16 * 256);
                #pragma unroll
                for (int nt = 0; nt < 7; ++nt) {
                    const bf16x8 bf = *(const bf16x8*)((const char*)lds +
                        nbase[nt] + (ky * HP + kx) * COLB);
                    #pragma unroll
                    for (int mt = 0; mt < 4; ++mt)
                        acc[mt][nt] = __builtin_amdgcn_mfma_f32_16x16x32_bf16(
                            a[mt], bf, acc[mt][nt], 0, 0, 0);
                }
            }
        }
        __syncthreads();
    }

    // epilogue: C/D layout col=lane&15 (pixel), row=(lane>>4)*4+reg (cout)
    #pragma unroll
    for (int mt = 0; mt < 4; ++mt) {
        #pragma unroll
        for (int nt = 0; nt < 7; ++nt) {
            const int p = nt * 16 + ln;
            const int yy = y0 + p / HH, xx = p % HH;
            #pragma unroll
            for (int r = 0; r < 4; ++r) {
                const int cout = mwave + mt * 16 + g * 4 + r;
                out[(size_t)(((b * 256 + cout) * HH + yy)) * HH + xx] = acc[mt][nt][r];
            }
        }
    }
}

// ---------------------------------------------------------------------------
extern "C" void kernel_launch(void* const* d_in, const int* in_sizes, int n_in,
                              void* d_out, int out_size, void* d_ws, size_t ws_size,
                              hipStream_t stream) {
    const float* x      = (const float*)d_in[0];
    const float* weight = (const float*)d_in[1];
    const float* am     = (const float*)d_in[2];
    const float* w1     = (const float*)d_in[3];
    const float* w2     = (const float*)d_in[4];
    const float* b2     = (const float*)d_in[5];
    float* out = (float*)d_out;
    char* ws = (char*)d_ws;

    float* s             = (float*)(ws + OFF_S);
    float* attn          = (float*)(ws + OFF_ATTN);
    float* wal           = (float*)(ws + OFF_WAL);
    unsigned short* aggw = (unsigned short*)(ws + OFF_AGGW);
    unsigned short* xpad = (unsigned short*)(ws + OFF_XPAD);

    hipMemsetAsync(s, 0, BATCH * 256 * sizeof(float), stream);
    border_kernel<<<dim3(4, BATCH), 256, 0, stream>>>(xpad);
    xprep_kernel<<<dim3(HH, BATCH), 256, 0, stream>>>(x, xpad, s);
    attn_kernel<<<BATCH, 128, 0, stream>>>(s, w1, w2, b2, attn);
    align_kernel<<<dim3(18, 4, NEXP), 256, 0, stream>>>(am, weight, wal);
    agg_kernel<<<2304, 256, 0, stream>>>(wal, attn, aggw);
    conv_kernel<<<dim3(28, BATCH), 256, 0, stream>>>(xpad, aggw, out);
}

// Round 2
// 513.273 us; speedup vs baseline: 1.0211x; 1.0211x over previous
//
#include <hip/hip_runtime.h>
#include <hip/hip_bf16.h>

// Problem constants
#define BATCH 32
#define CIN   256
#define COUT  256
#define HH    56
#define HP    58      // padded
#define NEXP  5
#define HID   65

// Workspace layout (bytes)
#define OFF_S     0                         // 32*256*4      = 32768
#define OFF_ATTN  32768                     // 32*5*4        = 640
#define OFF_WAL   65536                     // 5*9*256*256*4 = 11796480
#define OFF_AGGW  (12u*1024u*1024u)         // 32*9*256*256*2 = 37748736
#define OFF_XPAD  (48u*1024u*1024u)         // 32*58*58*256*2 = 55115776
// total ~ 101 MB

typedef __bf16 bf16x8 __attribute__((ext_vector_type(8)));
typedef float  f32x4  __attribute__((ext_vector_type(4)));

__device__ __forceinline__ unsigned short f2bf(float f) {
    unsigned int u = __float_as_uint(f);
    unsigned int r = (u + 0x7FFFu + ((u >> 16) & 1u)) >> 16;
    return (unsigned short)r;
}

// ---------------------------------------------------------------------------
// k1: zero the 1-px border of xpad (NHWC padded bf16)
// grid (4, 32), block 256
__global__ void border_kernel(unsigned short* __restrict__ xpad) {
    const int b = blockIdx.y, seg = blockIdx.x, tid = threadIdx.x;
    const uint4 z = make_uint4(0, 0, 0, 0);
    if (seg < 2) {
        const int y = seg ? (HP - 1) : 0;
        uint4* p = (uint4*)(xpad + (size_t)((b * HP + y) * HP) * 256);
        for (int i = tid; i < HP * 256 / 8; i += 256) p[i] = z;
    } else {
        const int xx = (seg == 2) ? 0 : (HP - 1);
        for (int i = tid; i < HP * 32; i += 256) {   // 58 rows x 32 uint4
            const int y = i >> 5, sub = i & 31;
            uint4* p = (uint4*)(xpad + (size_t)(((b * HP + y) * HP + xx)) * 256);
            p[sub] = z;
        }
    }
}

// ---------------------------------------------------------------------------
// k2: x (NCHW f32) -> xpad interior (NHWC bf16), fused global-avg-pool partials
// grid (56, 32), block 256
#define LP 260   // lds pitch (ushort), 520 B -> 8B-aligned rows, bank stride 2
__global__ void xprep_kernel(const float* __restrict__ x,
                             unsigned short* __restrict__ xpad,
                             float* __restrict__ s) {
    const int y = blockIdx.x, b = blockIdx.y;
    const int tid = threadIdx.x, lane = tid & 63, wg = tid >> 6;
    __shared__ unsigned short lds[HH * LP];   // [x][c]

    for (int c = wg; c < 256; c += 4) {
        float v = 0.f;
        if (lane < HH) v = x[(size_t)((b * 256 + c) * HH + y) * HH + lane];
        if (lane < HH) lds[lane * LP + c] = f2bf(v);
        float sum = v;
        #pragma unroll
        for (int off = 32; off > 0; off >>= 1) sum += __shfl_down(sum, off, 64);
        if (lane == 0) atomicAdd(&s[b * 256 + c], sum);
    }
    __syncthreads();
    // write out: 8 B per thread-iter, 14 iters
    for (int i = tid; i < HH * 64; i += 256) {
        const int xx = i >> 6, cg = (i & 63) * 4;
        uint2 v;
        v.x = *(const unsigned int*)&lds[xx * LP + cg];
        v.y = *(const unsigned int*)&lds[xx * LP + cg + 2];
        *(uint2*)(xpad + (size_t)(((b * HP + (y + 1)) * HP + (xx + 1))) * 256 + cg) = v;
    }
}

// ---------------------------------------------------------------------------
// k3: attention MLP.  grid 32, block 128
__global__ void attn_kernel(const float* __restrict__ s,
                            const float* __restrict__ w1,
                            const float* __restrict__ w2,
                            const float* __restrict__ b2,
                            float* __restrict__ attn) {
    const int b = blockIdx.x, tid = threadIdx.x;
    __shared__ float sm[256];
    __shared__ float hm[HID];
    for (int i = tid; i < 256; i += 128) sm[i] = s[b * 256 + i] * (1.f / 3136.f);
    __syncthreads();
    if (tid < HID) {
        float acc = 0.f;
        for (int c = 0; c < 256; ++c) acc += sm[c] * w1[tid * 256 + c];
        hm[tid] = fmaxf(acc, 0.f);
    }
    __syncthreads();
    if (tid < NEXP) {
        float acc = b2[tid];
        for (int j = 0; j < HID; ++j) acc += hm[j] * w2[tid * HID + j];
        attn[b * NEXP + tid] = 1.f / (1.f + expf(-acc));
    }
}

// ---------------------------------------------------------------------------
// k4: w_aligned[e,t,j,i] = sum_o align[e,j,o] * W[e,o,i*9+t]   (fp32)
// grid (18, 4, 5): n-tile(128), j-tile(64), e.  block 256.
__global__ void align_kernel(const float* __restrict__ am,
                             const float* __restrict__ w,
                             float* __restrict__ wal) {
    const int nt = blockIdx.x, jt = blockIdx.y, e = blockIdx.z;
    const int tid = threadIdx.x;
    const int tj = tid >> 5, tn = tid & 31;
    __shared__ float At[64][33];
    __shared__ float Wt[32][128];
    float acc[8][4];
    #pragma unroll
    for (int a = 0; a < 8; ++a)
        #pragma unroll
        for (int c = 0; c < 4; ++c) acc[a][c] = 0.f;

    for (int o0 = 0; o0 < 256; o0 += 32) {
        {   // stage align tile 64x32
            const int row = tid >> 2, col = (tid & 3) * 8;
            const float* src = am + (size_t)((e * 256) + jt * 64 + row) * 256 + o0 + col;
            float4 v0 = *(const float4*)(src);
            float4 v1 = *(const float4*)(src + 4);
            *(float4*)&At[row][col] = v0;
            *(float4*)&At[row][col + 4] = v1;
        }
        {   // stage W tile 32x128
            const int row = tid >> 3, col = (tid & 7) * 16;
            const float* src = w + (size_t)((e * 256) + o0 + row) * 2304 + nt * 128 + col;
            #pragma unroll
            for (int q = 0; q < 4; ++q)
                *(float4*)&Wt[row][col + q * 4] = *(const float4*)(src + q * 4);
        }
        __syncthreads();
        for (int k = 0; k < 32; ++k) {
            float wv[4];
            #pragma unroll
            for (int c = 0; c < 4; ++c) wv[c] = Wt[k][tn * 4 + c];
            #pragma unroll
            for (int a = 0; a < 8; ++a) {
                const float av = At[tj * 8 + a][k];
                #pragma unroll
                for (int c = 0; c < 4; ++c) acc[a][c] += av * wv[c];
            }
        }
        __syncthreads();
    }
    #pragma unroll
    for (int a = 0; a < 8; ++a) {
        const int j = jt * 64 + tj * 8 + a;
        #pragma unroll
        for (int c = 0; c < 4; ++c) {
            const int n = nt * 128 + tn * 4 + c;
            const int t = n % 9, i = n / 9;
            wal[(size_t)(((e * 9 + t) * 256 + j)) * 256 + i] = acc[a][c];
        }
    }
}

// ---------------------------------------------------------------------------
// k5: agg_w[b,t,j,i] (bf16) = sum_e attn[b,e] * wal[e,t,j,i]
// grid 2304 (t*256+j), block 256 (i)
__global__ void agg_kernel(const float* __restrict__ wal,
                           const float* __restrict__ attn,
                           unsigned short* __restrict__ aggw) {
    const int t = blockIdx.x >> 8, j = blockIdx.x & 255, i = threadIdx.x;
    __shared__ float at[BATCH * NEXP];
    if (threadIdx.x < BATCH * NEXP) at[threadIdx.x] = attn[threadIdx.x];
    float wv[NEXP];
    #pragma unroll
    for (int e = 0; e < NEXP; ++e)
        wv[e] = wal[(size_t)(((e * 9 + t) * 256 + j)) * 256 + i];
    __syncthreads();
    for (int b = 0; b < BATCH; ++b) {
        float acc = 0.f;
        #pragma unroll
        for (int e = 0; e < NEXP; ++e) acc += at[b * NEXP + e] * wv[e];
        aggw[(size_t)(((b * 9 + t) * 256 + j)) * 256 + i] = f2bf(acc);
    }
}

// ---------------------------------------------------------------------------
// k6: implicit-GEMM conv. block = 1 sample x 256 couts x 2 output rows (112 px)
// 1D grid 896 with XCD-aware remap: xcd = blk&7 owns 4 consecutive samples;
// within an XCD, the 28 row-blocks of a sample dispatch consecutively so
// aggw[b] (1.18 MB) stays L2-resident on that XCD.
// block 256 (4 waves; wave w -> couts [64w, 64w+64))
// LDS: input slab [4 rows][58 cols][32 ch pad->34] bf16
// CPAD=34 -> column stride 68 B = 17 banks (odd): 16 distinct banks over the
// 16 ln-lanes, 2-way aliasing over 64 lanes = conflict-free (m136).
#define CPAD 34
#define COLB (CPAD * 2)          // 68 B per col
#define ROWB (HP * COLB)         // 3944 B per row
__global__ __launch_bounds__(256, 2) void conv_kernel(
        const unsigned short* __restrict__ xpad,
        const unsigned short* __restrict__ aggw,
        float* __restrict__ out) {
    const int blk = blockIdx.x;
    const int xcd = blk & 7, slot = blk >> 3;       // slot 0..111
    const int b = xcd * 4 + slot / 28;
    const int y0 = (slot % 28) * 2;
    const int tid = threadIdx.x;
    const int wave = tid >> 6, lane = tid & 63;
    const int g = lane >> 4, ln = lane & 15;

    __shared__ unsigned short lds[4 * HP * CPAD];

    f32x4 acc[4][7];
    #pragma unroll
    for (int mt = 0; mt < 4; ++mt)
        #pragma unroll
        for (int nt = 0; nt < 7; ++nt) acc[mt][nt] = (f32x4){0.f, 0.f, 0.f, 0.f};

    // per-lane B-fragment base byte offsets (ky=kx=0)
    int nbase[7];
    #pragma unroll
    for (int nt = 0; nt < 7; ++nt) {
        const int p = nt * 16 + ln;
        const int yy = p / HH, xx = p % HH;
        nbase[nt] = (yy * HP + xx) * COLB + g * 16;
    }
    const int mwave = wave * 64;

    #pragma unroll 1
    for (int c0 = 0; c0 < 256; c0 += 32) {
        // stage 4 rows x 58 cols x 32 ch = 928 x 16B
        #pragma unroll
        for (int it = 0; it < 4; ++it) {
            const int idx = it * 256 + tid;
            if (idx < 928) {
                const int row = idx / 232;
                const int rem = idx - row * 232;
                const int col = rem >> 2, sub = rem & 3;
                const uint4 v = *(const uint4*)(xpad +
                    (size_t)(((b * HP + y0 + row) * HP + col)) * 256 + c0 + sub * 8);
                *(uint4*)((char*)lds + row * ROWB + col * COLB + sub * 16) = v;
            }
        }
        __syncthreads();

        #pragma unroll
        for (int ky = 0; ky < 3; ++ky) {
            #pragma unroll
            for (int kx = 0; kx < 3; ++kx) {
                const int tap = ky * 3 + kx;
                bf16x8 a[4];
                const unsigned short* ap = aggw +
                    (size_t)(((b * 9 + tap) * 256 + mwave + ln)) * 256 + c0 + g * 8;
                #pragma unroll
                for (int mt = 0; mt < 4; ++mt)
                    a[mt] = *(const bf16x8*)(ap + mt * 16 * 256);
                #pragma unroll
                for (int nt = 0; nt < 7; ++nt) {
                    const bf16x8 bf = *(const bf16x8*)((const char*)lds +
                        nbase[nt] + (ky * HP + kx) * COLB);
                    #pragma unroll
                    for (int mt = 0; mt < 4; ++mt)
                        acc[mt][nt] = __builtin_amdgcn_mfma_f32_16x16x32_bf16(
                            a[mt], bf, acc[mt][nt], 0, 0, 0);
                }
            }
        }
        __syncthreads();
    }

    // epilogue: C/D layout col=lane&15 (pixel), row=(lane>>4)*4+reg (cout)
    #pragma unroll
    for (int mt = 0; mt < 4; ++mt) {
        #pragma unroll
        for (int nt = 0; nt < 7; ++nt) {
            const int p = nt * 16 + ln;
            const int yy = y0 + p / HH, xx = p % HH;
            #pragma unroll
            for (int r = 0; r < 4; ++r) {
                const int cout = mwave + mt * 16 + g * 4 + r;
                out[(size_t)(((b * 256 + cout) * HH + yy)) * HH + xx] = acc[mt][nt][r];
            }
        }
    }
}

// ---------------------------------------------------------------------------
extern "C" void kernel_launch(void* const* d_in, const int* in_sizes, int n_in,
                              void* d_out, int out_size, void* d_ws, size_t ws_size,
                              hipStream_t stream) {
    const float* x      = (const float*)d_in[0];
    const float* weight = (const float*)d_in[1];
    const float* am     = (const float*)d_in[2];
    const float* w1     = (const float*)d_in[3];
    const float* w2     = (const float*)d_in[4];
    const float* b2     = (const float*)d_in[5];
    float* out = (float*)d_out;
    char* ws = (char*)d_ws;

    float* s             = (float*)(ws + OFF_S);
    float* attn          = (float*)(ws + OFF_ATTN);
    float* wal           = (float*)(ws + OFF_WAL);
    unsigned short* aggw = (unsigned short*)(ws + OFF_AGGW);
    unsigned short* xpad = (unsigned short*)(ws + OFF_XPAD);

    hipMemsetAsync(s, 0, BATCH * 256 * sizeof(float), stream);
    border_kernel<<<dim3(4, BATCH), 256, 0, stream>>>(xpad);
    xprep_kernel<<<dim3(HH, BATCH), 256, 0, stream>>>(x, xpad, s);
    attn_kernel<<<BATCH, 128, 0, stream>>>(s, w1, w2, b2, attn);
    align_kernel<<<dim3(18, 4, NEXP), 256, 0, stream>>>(am, weight, wal);
    agg_kernel<<<2304, 256, 0, stream>>>(wal, attn, aggw);
    conv_kernel<<<896, 256, 0, stream>>>(xpad, aggw, out);
}